// Round 8
// baseline (338.977 us; speedup 1.0000x reference)
//
#include <hip/hip_runtime.h>
#include <math.h>

typedef _Float16 f16x8 __attribute__((ext_vector_type(8)));
typedef float f32x4 __attribute__((ext_vector_type(4)));
typedef unsigned short us8 __attribute__((ext_vector_type(8)));

#define PI_F 3.14159265358979323846f

__device__ __forceinline__ void split16(float f, unsigned short& h, unsigned short& l){
  _Float16 hi = (_Float16)f;
  _Float16 lo = (_Float16)(f - (float)hi);
  h = __builtin_bit_cast(unsigned short, hi);
  l = __builtin_bit_cast(unsigned short, lo);
}

__device__ __forceinline__ float fast_gelu(float v){
  float u2 = v * v;
  float z  = v * fmaf(u2, 0.03567740814f, 0.7978845608f);
  float e  = __builtin_amdgcn_exp2f(z * 2.885390082f);   // 2*log2(e)
  float r  = __builtin_amdgcn_rcpf(e + 1.0f);
  return v - v * r;
}

__device__ __forceinline__ float fast_tanh(float v){
  float e = __builtin_amdgcn_exp2f(v * 2.885390082f);
  float r = __builtin_amdgcn_rcpf(e + 1.0f);
  return 1.0f - 2.0f * r;
}

// LDS tile addressing in ushort units, XOR swizzle for bank balance
#define ACOL(rr,cc) (((rr) << 8) + ((cc) ^ ((((rr) & 15)) << 3)))

#define LDW(ptr) __builtin_bit_cast(f16x8, *reinterpret_cast<const us8*>(ptr))

// ---------------- pyramid (jax.image.resize bilinear, antialias=True) -------
__global__ void pyr_kernel(const float* __restrict__ fg, float* __restrict__ out,
                           int Ho, int Wo, float inv_scale){
  int idx = blockIdx.x * blockDim.x + threadIdx.x;
  int total = 8 * Ho * Wo * 64;
  if (idx >= total) return;
  int c  = idx & 63;
  int xy = idx >> 6;
  int x  = xy % Wo;
  int y  = (xy / Wo) % Ho;
  int b  = xy / (Wo * Ho);
  float cyc = inv_scale * (y + 0.5f) - 0.5f;
  float cxc = inv_scale * (x + 0.5f) - 0.5f;
  int iy0 = (int)ceilf(cyc - inv_scale); if (iy0 < 0) iy0 = 0;
  int iy1 = (int)floorf(cyc + inv_scale); if (iy1 > 63) iy1 = 63;
  int ix0 = (int)ceilf(cxc - inv_scale); if (ix0 < 0) ix0 = 0;
  int ix1 = (int)floorf(cxc + inv_scale); if (ix1 > 63) ix1 = 63;
  float rinv = 1.0f / inv_scale;
  float wxs = 0.0f;
  for (int ix = ix0; ix <= ix1; ++ix){
    float w = 1.0f - fabsf(ix - cxc) * rinv;
    if (w > 0.0f) wxs += w;
  }
  float wys = 0.0f, acc = 0.0f;
  for (int iy = iy0; iy <= iy1; ++iy){
    float wy = 1.0f - fabsf(iy - cyc) * rinv;
    if (wy <= 0.0f) continue;
    wys += wy;
    const float* rowp = fg + (((b * 64) + iy) * 64) * 64 + c;
    for (int ix = ix0; ix <= ix1; ++ix){
      float wx = 1.0f - fabsf(ix - cxc) * rinv;
      if (wx <= 0.0f) continue;
      acc += wy * wx * rowp[ix * 64];
    }
  }
  out[idx] = acc / (wys * wxs);
}

// ------------- weight prep: pre-tiled per-lane MFMA fragments ---------------
// WT[l][cfg][ks][lane][e]: col = cfg*16 + (lane&15), k = ks*32 + (lane>>4)*8 + e
// layer0 k-remap: k<42 -> W0 row k; 42..47 pad; 48..239 -> row k-6; 240..255 pad
__global__ void prep_wt(const float* __restrict__ W0, const float* __restrict__ W1,
                        const float* __restrict__ W2, const float* __restrict__ W3,
                        unsigned short* __restrict__ WTh, unsigned short* __restrict__ WTl){
  int idx = blockIdx.x * 256 + threadIdx.x;      // < 262144
  int l    = idx >> 16;
  int cfg  = (idx >> 12) & 15;
  int ks   = (idx >> 9) & 7;
  int lane = (idx >> 3) & 63;
  int e    = idx & 7;
  int col  = cfg * 16 + (lane & 15);
  int k    = ks * 32 + (lane >> 4) * 8 + e;
  float v;
  if (l == 0){
    int row; bool valid;
    if (k < 42)                 { row = k;     valid = true; }
    else if (k >= 48 && k < 240){ row = k - 6; valid = true; }
    else                        { row = 0;     valid = false; }
    v = valid ? W0[row * 256 + col] : 0.0f;
  } else {
    const float* W = (l == 1) ? W1 : ((l == 2) ? W2 : W3);
    v = W[k * 256 + col];
  }
  unsigned short h, lo;
  split16(v, h, lo);
  WTh[idx] = h;
  WTl[idx] = lo;
}

// ------------- FiLM params + Wout tiled fragments ----------------------------
__global__ void prep_misc(const float* __restrict__ cv, const float* __restrict__ Wc,
                          const float* __restrict__ bc, const float* __restrict__ Wout,
                          float* __restrict__ gamma, float* __restrict__ beta,
                          unsigned short* __restrict__ WoT){
  int idx = blockIdx.x * 256 + threadIdx.x;      // < 8192
  if (idx < 4096){
    int b = idx >> 9, j = idx & 511;
    float a = bc[j];
    for (int c = 0; c < 64; ++c) a += cv[b * 64 + c] * Wc[c * 512 + j];
    if (j < 256) gamma[b * 256 + j] = a + 1.0f;
    else         beta[b * 256 + (j - 256)] = a;
  } else {
    int j = idx - 4096;                // WoT[ks][lane][e]
    int ks = j >> 9, lane = (j >> 3) & 63, e = j & 7;
    int col = lane & 15;
    int k = ks * 32 + (lane >> 4) * 8 + e;
    float v = (col < 3) ? Wout[k * 3 + col] : 0.0f;
    _Float16 h = (_Float16)v;
    WoT[j] = __builtin_bit_cast(unsigned short, h);
  }
}

// ------------------------------- main ---------------------------------------
// R4 numerics exactly; 512-thread blocks (8 waves x 32-col slices), same 64-row
// tile and grid decode. 64KB LDS -> 2 blocks/CU = 4 waves/SIMD.
__global__ __launch_bounds__(512, 4)
void dec_main(const float* __restrict__ fg, const float* __restrict__ coords,
              const float* __restrict__ p1, const float* __restrict__ p2,
              const unsigned short* __restrict__ WTh, const unsigned short* __restrict__ WTl,
              const unsigned short* __restrict__ WoT,
              const float* __restrict__ gamma, const float* __restrict__ beta,
              const float* __restrict__ b0, const float* __restrict__ b1,
              const float* __restrict__ b2, const float* __restrict__ b3,
              const float* __restrict__ bout, float* __restrict__ out){
  __shared__ __align__(16) unsigned short Ah[64 * 256];  // 32 KB hi tile
  __shared__ __align__(16) unsigned short Al[64 * 256];  // 32 KB lo tile

  const int t  = threadIdx.x;
  const int bi = blockIdx.x >> 8;           // image 0..7   (R4-validated decode)
  const int n0 = (blockIdx.x & 255) * 64;   // first coord row of this block

  const int lane = t & 63;
  const int wv   = t >> 6;         // 0..7
  const int cb   = wv * 32;        // this wave's 32-col slice
  const int l15  = lane & 15;
  const int lg   = lane >> 4;

  // FiLM params + biases for this lane's 2 columns (registers, R4-validated pattern)
  float gmv[2], btv[2], bsv[4][2];
#pragma unroll
  for (int cf = 0; cf < 2; ++cf){
    const int col = cb + cf * 16 + l15;
    gmv[cf] = gamma[bi * 256 + col];
    btv[cf] = beta[bi * 256 + col];
    bsv[0][cf] = b0[col]; bsv[1][cf] = b1[col];
    bsv[2][cf] = b2[col]; bsv[3][cf] = b3[col];
  }

  // ---------------- phase 0: build features (split f16, swizzled) ----------
  // R4-validated body verbatim, gated to t<256 (4 threads/row over 64 rows)
  if (t < 256){
    const int r = t >> 2, q = t & 3;
    const int n = n0 + r;
    const float cy = coords[2 * n], cx = coords[2 * n + 1];

    if (q == 0){
      float e[48];
      e[0] = cy; e[1] = cx;
#pragma unroll
      for (int i = 0; i < 10; ++i){
        float f = PI_F * (float)(1 << i);
        float sy, cyv, sx, cxv;
        sincosf(cy * f, &sy, &cyv);
        sincosf(cx * f, &sx, &cxv);
        e[2 + 4 * i] = sy;
        e[3 + 4 * i] = sx;
        e[4 + 4 * i] = cyv;
        e[5 + 4 * i] = cxv;
      }
#pragma unroll
      for (int j = 42; j < 48; ++j) e[j] = 0.0f;
#pragma unroll
      for (int u = 0; u < 6; ++u){
        us8 vh, vl;
#pragma unroll
        for (int j = 0; j < 8; ++j){
          unsigned short h, l;
          split16(e[8 * u + j], h, l);
          vh[j] = h; vl[j] = l;
        }
        *reinterpret_cast<us8*>(&Ah[ACOL(r, u * 8)]) = vh;
        *reinterpret_cast<us8*>(&Al[ACOL(r, u * 8)]) = vl;
      }
    }
    if (q == 1){   // zero pad cols 240..255
      us8 z = {0,0,0,0,0,0,0,0};
      *reinterpret_cast<us8*>(&Ah[ACOL(r, 240)]) = z;
      *reinterpret_cast<us8*>(&Ah[ACOL(r, 248)]) = z;
      *reinterpret_cast<us8*>(&Al[ACOL(r, 240)]) = z;
      *reinterpret_cast<us8*>(&Al[ACOL(r, 248)]) = z;
    }

    // bilinear sample 16 channels per thread from each pyramid level
#pragma unroll
    for (int L = 0; L < 3; ++L){
      const int HL = 64 >> L;
      const float* g = (L == 0) ? fg : ((L == 1) ? p1 : p2);
      float yy = (cy + 1.0f) * 0.5f * (HL - 1);
      float xx = (cx + 1.0f) * 0.5f * (HL - 1);
      float y0f = floorf(yy), x0f = floorf(xx);
      float wy = yy - y0f, wx = xx - x0f;
      int y0 = (int)y0f, x0 = (int)x0f;
      y0 = min(max(y0, 0), HL - 1); x0 = min(max(x0, 0), HL - 1);
      int y1 = min(y0 + 1, HL - 1), x1 = min(x0 + 1, HL - 1);
      const int c0 = q * 16;
      const float* g00 = g + (((bi * HL + y0) * HL) + x0) * 64 + c0;
      const float* g01 = g + (((bi * HL + y0) * HL) + x1) * 64 + c0;
      const float* g10 = g + (((bi * HL + y1) * HL) + x0) * 64 + c0;
      const float* g11 = g + (((bi * HL + y1) * HL) + x1) * 64 + c0;
      float w00 = (1 - wy) * (1 - wx), w01 = (1 - wy) * wx;
      float w10 = wy * (1 - wx),       w11 = wy * wx;
      float o[16];
#pragma unroll
      for (int u = 0; u < 4; ++u){
        float4 v0 = *reinterpret_cast<const float4*>(g00 + 4 * u);
        float4 v1 = *reinterpret_cast<const float4*>(g01 + 4 * u);
        float4 v2 = *reinterpret_cast<const float4*>(g10 + 4 * u);
        float4 v3 = *reinterpret_cast<const float4*>(g11 + 4 * u);
        o[4*u+0] = w00*v0.x + w01*v1.x + w10*v2.x + w11*v3.x;
        o[4*u+1] = w00*v0.y + w01*v1.y + w10*v2.y + w11*v3.y;
        o[4*u+2] = w00*v0.z + w01*v1.z + w10*v2.z + w11*v3.z;
        o[4*u+3] = w00*v0.w + w01*v1.w + w10*v2.w + w11*v3.w;
      }
      us8 h0, h1, l0, l1;
#pragma unroll
      for (int j = 0; j < 8; ++j){
        unsigned short h, l;
        split16(o[j], h, l);      h0[j] = h; l0[j] = l;
        split16(o[8 + j], h, l);  h1[j] = h; l1[j] = l;
      }
      const int colb = 48 + 64 * L + 16 * q;
      *reinterpret_cast<us8*>(&Ah[ACOL(r, colb)])     = h0;
      *reinterpret_cast<us8*>(&Ah[ACOL(r, colb + 8)]) = h1;
      *reinterpret_cast<us8*>(&Al[ACOL(r, colb)])     = l0;
      *reinterpret_cast<us8*>(&Al[ACOL(r, colb + 8)]) = l1;
    }
  }
  __syncthreads();

  // ---------------- phase 1: 4 FiLM-gelu MLP layers (split f16) ------------
  // B fragments pre-tiled: offset = cfg*4096 + ks*512 + lane*8, cfg = wv*2+cf
  const int bbase = wv * 8192 + lane * 8;

  for (int l = 0; l < 4; ++l){
    f32x4 acc[4][2];
#pragma unroll
    for (int rf = 0; rf < 4; ++rf)
#pragma unroll
      for (int cf = 0; cf < 2; ++cf)
        acc[rf][cf] = (f32x4){0.0f, 0.0f, 0.0f, 0.0f};

    const unsigned short* Wh  = WTh + l * 65536;
    const unsigned short* Wl_ = WTl + l * 65536;

    f16x8 bh[2][2], bl[2][2];
#pragma unroll
    for (int cf = 0; cf < 2; ++cf){
      bh[0][cf] = LDW(Wh  + bbase + cf * 4096);
      bl[0][cf] = LDW(Wl_ + bbase + cf * 4096);
    }

#pragma unroll
    for (int ks = 0; ks < 8; ++ks){
      const int cur = ks & 1, nxt = cur ^ 1;
      if (ks < 7){
#pragma unroll
        for (int cf = 0; cf < 2; ++cf){
          bh[nxt][cf] = LDW(Wh  + bbase + cf * 4096 + (ks + 1) * 512);
          bl[nxt][cf] = LDW(Wl_ + bbase + cf * 4096 + (ks + 1) * 512);
        }
      }
      const int kc = ks * 32 + lg * 8;
      f16x8 ah[4], alv[4];
#pragma unroll
      for (int rf = 0; rf < 4; ++rf){
        ah[rf]  = LDW(&Ah[ACOL(rf * 16 + l15, kc)]);
        alv[rf] = LDW(&Al[ACOL(rf * 16 + l15, kc)]);
      }
#pragma unroll
      for (int cf = 0; cf < 2; ++cf){
#pragma unroll
        for (int rf = 0; rf < 4; ++rf){
          acc[rf][cf] = __builtin_amdgcn_mfma_f32_16x16x32_f16(ah[rf],  bh[cur][cf], acc[rf][cf], 0, 0, 0);
          acc[rf][cf] = __builtin_amdgcn_mfma_f32_16x16x32_f16(alv[rf], bh[cur][cf], acc[rf][cf], 0, 0, 0);
          acc[rf][cf] = __builtin_amdgcn_mfma_f32_16x16x32_f16(ah[rf],  bl[cur][cf], acc[rf][cf], 0, 0, 0);
        }
      }
    }
    __syncthreads();   // all reads of tiles done before overwrite

#pragma unroll
    for (int rf = 0; rf < 4; ++rf){
#pragma unroll
      for (int cf = 0; cf < 2; ++cf){
        const int col = cb + cf * 16 + l15;
        const float gm = gmv[cf], bt = btv[cf], bs = bsv[l][cf];
#pragma unroll
        for (int rg = 0; rg < 4; ++rg){
          const int row = rf * 16 + lg * 4 + rg;   // measured C/D layout (m89)
          float v = fmaf(acc[rf][cf][rg] + bs, gm, bt);
          float gg = fast_gelu(v);
          unsigned short h, lo;
          split16(gg, h, lo);
          Ah[ACOL(row, col)] = h;
          Al[ACOL(row, col)] = lo;
        }
      }
    }
    __syncthreads();
  }

  // ---------------- phase 2: output head (256 -> 3) + tanh ------------------
  if (wv < 4){
    f32x4 ao = (f32x4){0.0f, 0.0f, 0.0f, 0.0f};
#pragma unroll
    for (int ks = 0; ks < 8; ++ks){
      const int kc = ks * 32 + lg * 8;
      f16x8 va = LDW(&Ah[ACOL(wv * 16 + l15, kc)]);
      f16x8 vl = LDW(&Al[ACOL(wv * 16 + l15, kc)]);
      f16x8 vb = LDW(&WoT[(ks * 64 + lane) * 8]);
      ao = __builtin_amdgcn_mfma_f32_16x16x32_f16(va, vb, ao, 0, 0, 0);
      ao = __builtin_amdgcn_mfma_f32_16x16x32_f16(vl, vb, ao, 0, 0, 0);
    }
    if (l15 < 3){
      const float bo = bout[l15];
#pragma unroll
      for (int rg = 0; rg < 4; ++rg){
        const int row = wv * 16 + lg * 4 + rg;
        out[((size_t)bi * 16384 + n0 + row) * 3 + l15] = fast_tanh(ao[rg] + bo);
      }
    }
  }
}

// ------------------------------- launch --------------------------------------
extern "C" void kernel_launch(void* const* d_in, const int* in_sizes, int n_in,
                              void* d_out, int out_size, void* d_ws, size_t ws_size,
                              hipStream_t stream){
  (void)in_sizes; (void)n_in; (void)out_size; (void)ws_size;
  const float* fg     = (const float*)d_in[0];
  const float* cv     = (const float*)d_in[1];
  const float* coords = (const float*)d_in[2];
  const float* Wc     = (const float*)d_in[3];
  const float* bc     = (const float*)d_in[4];
  const float* W0     = (const float*)d_in[5];
  const float* b0     = (const float*)d_in[6];
  const float* W1     = (const float*)d_in[7];
  const float* b1     = (const float*)d_in[8];
  const float* W2     = (const float*)d_in[9];
  const float* b2     = (const float*)d_in[10];
  const float* W3     = (const float*)d_in[11];
  const float* b3     = (const float*)d_in[12];
  const float* Wout   = (const float*)d_in[13];
  const float* bout   = (const float*)d_in[14];

  char* ws = (char*)d_ws;
  float*          p1    = (float*)(ws);                    // 8*32*32*64 f32 = 2 MB
  float*          p2    = (float*)(ws + 2097152);          // 8*16*16*64 f32 = 512 KB
  unsigned short* WTh   = (unsigned short*)(ws + 2621440); // 4*256*256 f16 = 512 KB
  unsigned short* WTl   = (unsigned short*)(ws + 3145728); // 512 KB
  unsigned short* WoT   = (unsigned short*)(ws + 3670016); // 8*64*8 f16
  float*          gam   = (float*)(ws + 3678208);          // 8*256 f32
  float*          bet   = (float*)(ws + 3686400);          // 8*256 f32
  float*          outp  = (float*)d_out;

  pyr_kernel<<<dim3(2048), dim3(256), 0, stream>>>(fg, p1, 32, 32, 2.0f);
  pyr_kernel<<<dim3(512),  dim3(256), 0, stream>>>(fg, p2, 16, 16, 4.0f);
  prep_wt  <<<dim3(1024),  dim3(256), 0, stream>>>(W0, W1, W2, W3, WTh, WTl);
  prep_misc<<<dim3(32),    dim3(256), 0, stream>>>(cv, Wc, bc, Wout, gam, bet, WoT);
  dec_main <<<dim3(2048),  dim3(512), 0, stream>>>(fg, coords, p1, p2, WTh, WTl, WoT,
                                                   gam, bet, b0, b1, b2, b3, bout, outp);
}

// Round 10
// 306.955 us; speedup vs baseline: 1.1043x; 1.1043x over previous
//
#include <hip/hip_runtime.h>
#include <math.h>

typedef _Float16 f16x8 __attribute__((ext_vector_type(8)));
typedef float f32x4 __attribute__((ext_vector_type(4)));
typedef unsigned short us8 __attribute__((ext_vector_type(8)));

#define PI_F 3.14159265358979323846f

__device__ __forceinline__ void split16(float f, unsigned short& h, unsigned short& l){
  _Float16 hi = (_Float16)f;
  _Float16 lo = (_Float16)(f - (float)hi);
  h = __builtin_bit_cast(unsigned short, hi);
  l = __builtin_bit_cast(unsigned short, lo);
}

__device__ __forceinline__ float fast_gelu(float v){
  float u2 = v * v;
  float z  = v * fmaf(u2, 0.03567740814f, 0.7978845608f);
  float e  = __builtin_amdgcn_exp2f(z * 2.885390082f);   // 2*log2(e)
  float r  = __builtin_amdgcn_rcpf(e + 1.0f);
  return v - v * r;
}

__device__ __forceinline__ float fast_tanh(float v){
  float e = __builtin_amdgcn_exp2f(v * 2.885390082f);
  float r = __builtin_amdgcn_rcpf(e + 1.0f);
  return 1.0f - 2.0f * r;
}

// LDS tile addressing in ushort units, XOR swizzle for bank balance
#define ACOL(rr,cc) (((rr) << 8) + ((cc) ^ ((((rr) & 15)) << 3)))

#define LDW(ptr) __builtin_bit_cast(f16x8, *reinterpret_cast<const us8*>(ptr))

// ---------------- pyramid (jax.image.resize bilinear, antialias=True) -------
__global__ void pyr_kernel(const float* __restrict__ fg, float* __restrict__ out,
                           int Ho, int Wo, float inv_scale){
  int idx = blockIdx.x * blockDim.x + threadIdx.x;
  int total = 8 * Ho * Wo * 64;
  if (idx >= total) return;
  int c  = idx & 63;
  int xy = idx >> 6;
  int x  = xy % Wo;
  int y  = (xy / Wo) % Ho;
  int b  = xy / (Wo * Ho);
  float cyc = inv_scale * (y + 0.5f) - 0.5f;
  float cxc = inv_scale * (x + 0.5f) - 0.5f;
  int iy0 = (int)ceilf(cyc - inv_scale); if (iy0 < 0) iy0 = 0;
  int iy1 = (int)floorf(cyc + inv_scale); if (iy1 > 63) iy1 = 63;
  int ix0 = (int)ceilf(cxc - inv_scale); if (ix0 < 0) ix0 = 0;
  int ix1 = (int)floorf(cxc + inv_scale); if (ix1 > 63) ix1 = 63;
  float rinv = 1.0f / inv_scale;
  float wxs = 0.0f;
  for (int ix = ix0; ix <= ix1; ++ix){
    float w = 1.0f - fabsf(ix - cxc) * rinv;
    if (w > 0.0f) wxs += w;
  }
  float wys = 0.0f, acc = 0.0f;
  for (int iy = iy0; iy <= iy1; ++iy){
    float wy = 1.0f - fabsf(iy - cyc) * rinv;
    if (wy <= 0.0f) continue;
    wys += wy;
    const float* rowp = fg + (((b * 64) + iy) * 64) * 64 + c;
    for (int ix = ix0; ix <= ix1; ++ix){
      float wx = 1.0f - fabsf(ix - cxc) * rinv;
      if (wx <= 0.0f) continue;
      acc += wy * wx * rowp[ix * 64];
    }
  }
  out[idx] = acc / (wys * wxs);
}

// ------------- weight prep: pre-tiled per-lane MFMA fragments ---------------
// WT[l][cfg][ks][lane][e]: col = cfg*16 + (lane&15), k = ks*32 + (lane>>4)*8 + e
// layer0 k-remap: k<42 -> W0 row k; 42..47 pad; 48..239 -> row k-6; 240..255 pad
__global__ void prep_wt(const float* __restrict__ W0, const float* __restrict__ W1,
                        const float* __restrict__ W2, const float* __restrict__ W3,
                        unsigned short* __restrict__ WTh, unsigned short* __restrict__ WTl){
  int idx = blockIdx.x * 256 + threadIdx.x;      // < 262144
  int l    = idx >> 16;
  int cfg  = (idx >> 12) & 15;
  int ks   = (idx >> 9) & 7;
  int lane = (idx >> 3) & 63;
  int e    = idx & 7;
  int col  = cfg * 16 + (lane & 15);
  int k    = ks * 32 + (lane >> 4) * 8 + e;
  float v;
  if (l == 0){
    int row; bool valid;
    if (k < 42)                 { row = k;     valid = true; }
    else if (k >= 48 && k < 240){ row = k - 6; valid = true; }
    else                        { row = 0;     valid = false; }
    v = valid ? W0[row * 256 + col] : 0.0f;
  } else {
    const float* W = (l == 1) ? W1 : ((l == 2) ? W2 : W3);
    v = W[k * 256 + col];
  }
  unsigned short h, lo;
  split16(v, h, lo);
  WTh[idx] = h;
  WTl[idx] = lo;
}

// ------------- FiLM params + Wout tiled fragments ----------------------------
__global__ void prep_misc(const float* __restrict__ cv, const float* __restrict__ Wc,
                          const float* __restrict__ bc, const float* __restrict__ Wout,
                          float* __restrict__ gamma, float* __restrict__ beta,
                          unsigned short* __restrict__ WoT){
  int idx = blockIdx.x * 256 + threadIdx.x;      // < 8192
  if (idx < 4096){
    int b = idx >> 9, j = idx & 511;
    float a = bc[j];
    for (int c = 0; c < 64; ++c) a += cv[b * 64 + c] * Wc[c * 512 + j];
    if (j < 256) gamma[b * 256 + j] = a + 1.0f;
    else         beta[b * 256 + (j - 256)] = a;
  } else {
    int j = idx - 4096;                // WoT[ks][lane][e]
    int ks = j >> 9, lane = (j >> 3) & 63, e = j & 7;
    int col = lane & 15;
    int k = ks * 32 + (lane >> 4) * 8 + e;
    float v = (col < 3) ? Wout[k * 3 + col] : 0.0f;
    _Float16 h = (_Float16)v;
    WoT[j] = __builtin_bit_cast(unsigned short, h);
  }
}

// ------------------------------- main ---------------------------------------
// R8 verbatim except launch_bounds 2nd arg 4 -> 2: empirical semantics on this
// compiler is blocks/CU, so cap = 131072/(2*512) = 128 VGPR (R8's =4 gave 64
// and spilled ~500MB/dispatch to scratch). LDS still limits to 2 blocks/CU.
__global__ __launch_bounds__(512, 2)
void dec_main(const float* __restrict__ fg, const float* __restrict__ coords,
              const float* __restrict__ p1, const float* __restrict__ p2,
              const unsigned short* __restrict__ WTh, const unsigned short* __restrict__ WTl,
              const unsigned short* __restrict__ WoT,
              const float* __restrict__ gamma, const float* __restrict__ beta,
              const float* __restrict__ b0, const float* __restrict__ b1,
              const float* __restrict__ b2, const float* __restrict__ b3,
              const float* __restrict__ bout, float* __restrict__ out){
  __shared__ __align__(16) unsigned short Ah[64 * 256];  // 32 KB hi tile
  __shared__ __align__(16) unsigned short Al[64 * 256];  // 32 KB lo tile

  const int t  = threadIdx.x;
  const int bi = blockIdx.x >> 8;           // image 0..7   (R4-validated decode)
  const int n0 = (blockIdx.x & 255) * 64;   // first coord row of this block

  const int lane = t & 63;
  const int wv   = t >> 6;         // 0..7
  const int cb   = wv * 32;        // this wave's 32-col slice
  const int l15  = lane & 15;
  const int lg   = lane >> 4;

  // FiLM params + biases for this lane's 2 columns (registers, R8-validated)
  float gmv[2], btv[2], bsv[4][2];
#pragma unroll
  for (int cf = 0; cf < 2; ++cf){
    const int col = cb + cf * 16 + l15;
    gmv[cf] = gamma[bi * 256 + col];
    btv[cf] = beta[bi * 256 + col];
    bsv[0][cf] = b0[col]; bsv[1][cf] = b1[col];
    bsv[2][cf] = b2[col]; bsv[3][cf] = b3[col];
  }

  // ---------------- phase 0: build features (split f16, swizzled) ----------
  // R4-validated body verbatim, gated to t<256 (4 threads/row over 64 rows)
  if (t < 256){
    const int r = t >> 2, q = t & 3;
    const int n = n0 + r;
    const float cy = coords[2 * n], cx = coords[2 * n + 1];

    if (q == 0){
      float e[48];
      e[0] = cy; e[1] = cx;
#pragma unroll
      for (int i = 0; i < 10; ++i){
        float f = PI_F * (float)(1 << i);
        float sy, cyv, sx, cxv;
        sincosf(cy * f, &sy, &cyv);
        sincosf(cx * f, &sx, &cxv);
        e[2 + 4 * i] = sy;
        e[3 + 4 * i] = sx;
        e[4 + 4 * i] = cyv;
        e[5 + 4 * i] = cxv;
      }
#pragma unroll
      for (int j = 42; j < 48; ++j) e[j] = 0.0f;
#pragma unroll
      for (int u = 0; u < 6; ++u){
        us8 vh, vl;
#pragma unroll
        for (int j = 0; j < 8; ++j){
          unsigned short h, l;
          split16(e[8 * u + j], h, l);
          vh[j] = h; vl[j] = l;
        }
        *reinterpret_cast<us8*>(&Ah[ACOL(r, u * 8)]) = vh;
        *reinterpret_cast<us8*>(&Al[ACOL(r, u * 8)]) = vl;
      }
    }
    if (q == 1){   // zero pad cols 240..255
      us8 z = {0,0,0,0,0,0,0,0};
      *reinterpret_cast<us8*>(&Ah[ACOL(r, 240)]) = z;
      *reinterpret_cast<us8*>(&Ah[ACOL(r, 248)]) = z;
      *reinterpret_cast<us8*>(&Al[ACOL(r, 240)]) = z;
      *reinterpret_cast<us8*>(&Al[ACOL(r, 248)]) = z;
    }

    // bilinear sample 16 channels per thread from each pyramid level
#pragma unroll
    for (int L = 0; L < 3; ++L){
      const int HL = 64 >> L;
      const float* g = (L == 0) ? fg : ((L == 1) ? p1 : p2);
      float yy = (cy + 1.0f) * 0.5f * (HL - 1);
      float xx = (cx + 1.0f) * 0.5f * (HL - 1);
      float y0f = floorf(yy), x0f = floorf(xx);
      float wy = yy - y0f, wx = xx - x0f;
      int y0 = (int)y0f, x0 = (int)x0f;
      y0 = min(max(y0, 0), HL - 1); x0 = min(max(x0, 0), HL - 1);
      int y1 = min(y0 + 1, HL - 1), x1 = min(x0 + 1, HL - 1);
      const int c0 = q * 16;
      const float* g00 = g + (((bi * HL + y0) * HL) + x0) * 64 + c0;
      const float* g01 = g + (((bi * HL + y0) * HL) + x1) * 64 + c0;
      const float* g10 = g + (((bi * HL + y1) * HL) + x0) * 64 + c0;
      const float* g11 = g + (((bi * HL + y1) * HL) + x1) * 64 + c0;
      float w00 = (1 - wy) * (1 - wx), w01 = (1 - wy) * wx;
      float w10 = wy * (1 - wx),       w11 = wy * wx;
      float o[16];
#pragma unroll
      for (int u = 0; u < 4; ++u){
        float4 v0 = *reinterpret_cast<const float4*>(g00 + 4 * u);
        float4 v1 = *reinterpret_cast<const float4*>(g01 + 4 * u);
        float4 v2 = *reinterpret_cast<const float4*>(g10 + 4 * u);
        float4 v3 = *reinterpret_cast<const float4*>(g11 + 4 * u);
        o[4*u+0] = w00*v0.x + w01*v1.x + w10*v2.x + w11*v3.x;
        o[4*u+1] = w00*v0.y + w01*v1.y + w10*v2.y + w11*v3.y;
        o[4*u+2] = w00*v0.z + w01*v1.z + w10*v2.z + w11*v3.z;
        o[4*u+3] = w00*v0.w + w01*v1.w + w10*v2.w + w11*v3.w;
      }
      us8 h0, h1, l0, l1;
#pragma unroll
      for (int j = 0; j < 8; ++j){
        unsigned short h, l;
        split16(o[j], h, l);      h0[j] = h; l0[j] = l;
        split16(o[8 + j], h, l);  h1[j] = h; l1[j] = l;
      }
      const int colb = 48 + 64 * L + 16 * q;
      *reinterpret_cast<us8*>(&Ah[ACOL(r, colb)])     = h0;
      *reinterpret_cast<us8*>(&Ah[ACOL(r, colb + 8)]) = h1;
      *reinterpret_cast<us8*>(&Al[ACOL(r, colb)])     = l0;
      *reinterpret_cast<us8*>(&Al[ACOL(r, colb + 8)]) = l1;
    }
  }
  __syncthreads();

  // ---------------- phase 1: 4 FiLM-gelu MLP layers (split f16) ------------
  // B fragments pre-tiled: offset = cfg*4096 + ks*512 + lane*8, cfg = wv*2+cf
  const int bbase = wv * 8192 + lane * 8;

  for (int l = 0; l < 4; ++l){
    f32x4 acc[4][2];
#pragma unroll
    for (int rf = 0; rf < 4; ++rf)
#pragma unroll
      for (int cf = 0; cf < 2; ++cf)
        acc[rf][cf] = (f32x4){0.0f, 0.0f, 0.0f, 0.0f};

    const unsigned short* Wh  = WTh + l * 65536;
    const unsigned short* Wl_ = WTl + l * 65536;

    f16x8 bh[2][2], bl[2][2];
#pragma unroll
    for (int cf = 0; cf < 2; ++cf){
      bh[0][cf] = LDW(Wh  + bbase + cf * 4096);
      bl[0][cf] = LDW(Wl_ + bbase + cf * 4096);
    }

#pragma unroll
    for (int ks = 0; ks < 8; ++ks){
      const int cur = ks & 1, nxt = cur ^ 1;
      if (ks < 7){
#pragma unroll
        for (int cf = 0; cf < 2; ++cf){
          bh[nxt][cf] = LDW(Wh  + bbase + cf * 4096 + (ks + 1) * 512);
          bl[nxt][cf] = LDW(Wl_ + bbase + cf * 4096 + (ks + 1) * 512);
        }
      }
      const int kc = ks * 32 + lg * 8;
      f16x8 ah[4], alv[4];
#pragma unroll
      for (int rf = 0; rf < 4; ++rf){
        ah[rf]  = LDW(&Ah[ACOL(rf * 16 + l15, kc)]);
        alv[rf] = LDW(&Al[ACOL(rf * 16 + l15, kc)]);
      }
#pragma unroll
      for (int cf = 0; cf < 2; ++cf){
#pragma unroll
        for (int rf = 0; rf < 4; ++rf){
          acc[rf][cf] = __builtin_amdgcn_mfma_f32_16x16x32_f16(ah[rf],  bh[cur][cf], acc[rf][cf], 0, 0, 0);
          acc[rf][cf] = __builtin_amdgcn_mfma_f32_16x16x32_f16(alv[rf], bh[cur][cf], acc[rf][cf], 0, 0, 0);
          acc[rf][cf] = __builtin_amdgcn_mfma_f32_16x16x32_f16(ah[rf],  bl[cur][cf], acc[rf][cf], 0, 0, 0);
        }
      }
    }
    __syncthreads();   // all reads of tiles done before overwrite

#pragma unroll
    for (int rf = 0; rf < 4; ++rf){
#pragma unroll
      for (int cf = 0; cf < 2; ++cf){
        const int col = cb + cf * 16 + l15;
        const float gm = gmv[cf], bt = btv[cf], bs = bsv[l][cf];
#pragma unroll
        for (int rg = 0; rg < 4; ++rg){
          const int row = rf * 16 + lg * 4 + rg;   // measured C/D layout (m89)
          float v = fmaf(acc[rf][cf][rg] + bs, gm, bt);
          float gg = fast_gelu(v);
          unsigned short h, lo;
          split16(gg, h, lo);
          Ah[ACOL(row, col)] = h;
          Al[ACOL(row, col)] = lo;
        }
      }
    }
    __syncthreads();
  }

  // ---------------- phase 2: output head (256 -> 3) + tanh ------------------
  if (wv < 4){
    f32x4 ao = (f32x4){0.0f, 0.0f, 0.0f, 0.0f};
#pragma unroll
    for (int ks = 0; ks < 8; ++ks){
      const int kc = ks * 32 + lg * 8;
      f16x8 va = LDW(&Ah[ACOL(wv * 16 + l15, kc)]);
      f16x8 vl = LDW(&Al[ACOL(wv * 16 + l15, kc)]);
      f16x8 vb = LDW(&WoT[(ks * 64 + lane) * 8]);
      ao = __builtin_amdgcn_mfma_f32_16x16x32_f16(va, vb, ao, 0, 0, 0);
      ao = __builtin_amdgcn_mfma_f32_16x16x32_f16(vl, vb, ao, 0, 0, 0);
    }
    if (l15 < 3){
      const float bo = bout[l15];
#pragma unroll
      for (int rg = 0; rg < 4; ++rg){
        const int row = wv * 16 + lg * 4 + rg;
        out[((size_t)bi * 16384 + n0 + row) * 3 + l15] = fast_tanh(ao[rg] + bo);
      }
    }
  }
}

// ------------------------------- launch --------------------------------------
extern "C" void kernel_launch(void* const* d_in, const int* in_sizes, int n_in,
                              void* d_out, int out_size, void* d_ws, size_t ws_size,
                              hipStream_t stream){
  (void)in_sizes; (void)n_in; (void)out_size; (void)ws_size;
  const float* fg     = (const float*)d_in[0];
  const float* cv     = (const float*)d_in[1];
  const float* coords = (const float*)d_in[2];
  const float* Wc     = (const float*)d_in[3];
  const float* bc     = (const float*)d_in[4];
  const float* W0     = (const float*)d_in[5];
  const float* b0     = (const float*)d_in[6];
  const float* W1     = (const float*)d_in[7];
  const float* b1     = (const float*)d_in[8];
  const float* W2     = (const float*)d_in[9];
  const float* b2     = (const float*)d_in[10];
  const float* W3     = (const float*)d_in[11];
  const float* b3     = (const float*)d_in[12];
  const float* Wout   = (const float*)d_in[13];
  const float* bout   = (const float*)d_in[14];

  char* ws = (char*)d_ws;
  float*          p1    = (float*)(ws);                    // 8*32*32*64 f32 = 2 MB
  float*          p2    = (float*)(ws + 2097152);          // 8*16*16*64 f32 = 512 KB
  unsigned short* WTh   = (unsigned short*)(ws + 2621440); // 4*256*256 f16 = 512 KB
  unsigned short* WTl   = (unsigned short*)(ws + 3145728); // 512 KB
  unsigned short* WoT   = (unsigned short*)(ws + 3670016); // 8*64*8 f16
  float*          gam   = (float*)(ws + 3678208);          // 8*256 f32
  float*          bet   = (float*)(ws + 3686400);          // 8*256 f32
  float*          outp  = (float*)d_out;

  pyr_kernel<<<dim3(2048), dim3(256), 0, stream>>>(fg, p1, 32, 32, 2.0f);
  pyr_kernel<<<dim3(512),  dim3(256), 0, stream>>>(fg, p2, 16, 16, 4.0f);
  prep_wt  <<<dim3(1024),  dim3(256), 0, stream>>>(W0, W1, W2, W3, WTh, WTl);
  prep_misc<<<dim3(32),    dim3(256), 0, stream>>>(cv, Wc, bc, Wout, gam, bet, WoT);
  dec_main <<<dim3(2048),  dim3(512), 0, stream>>>(fg, coords, p1, p2, WTh, WTl, WoT,
                                                   gam, bet, b0, b1, b2, b3, bout, outp);
}